// Round 6
// baseline (358.603 us; speedup 1.0000x reference)
//
#include <hip/hip_runtime.h>
#include <stdint.h>

// Problem constants (fixed by reference)
#define B_ROWS 8192
#define DH     1024      // D == H == 1024
#define KTOT   2048      // D + H (concatenated K)
#define NTOT   4096      // 4*H columns (gate-deinterleaved packing, see below)

typedef __attribute__((ext_vector_type(8))) __bf16 bf16x8;
typedef __attribute__((ext_vector_type(4))) float  f32x4;

// ---------- helpers ----------
__device__ __forceinline__ unsigned short f2bf(float f) {
    unsigned int u = __float_as_uint(f);
    u += 0x7FFFu + ((u >> 16) & 1u);   // round-to-nearest-even
    return (unsigned short)(u >> 16);
}

__device__ __forceinline__ float fast_sigmoid(float x) {
    return 1.0f / (1.0f + __expf(-x));
}
__device__ __forceinline__ float fast_tanh(float x) {
    float e = __expf(fminf(-2.0f * x, 80.0f));   // clamp avoids inf/inf
    return (1.0f - e) / (1.0f + e);
}

// ---------- single fused pack kernel (unchanged, verified) ----------
// N-space packing (gate-deinterleaved for the shuffle-free epilogue):
//   W_cat row n holds W row g = gate*DH + h with
//     gate = (n>>4) & 3,  h = (n>>6)*16 + (n&15)
//   bias[] packed identically.  The GEMM is invariant to this column perm.
#define NBLK_A (B_ROWS)            // one block packs one 2048-elem row
#define NBLK_W (NTOT)
#define NBLK_BIAS (NTOT / 256)

__global__ __launch_bounds__(256) void pack_all(const float* __restrict__ e_t,
                                                const float* __restrict__ h_prev,
                                                const float* __restrict__ W_x,
                                                const float* __restrict__ W_h,
                                                const float* __restrict__ b_x,
                                                const float* __restrict__ b_h,
                                                const float* __restrict__ b_e,
                                                unsigned short* __restrict__ A_cat,
                                                unsigned short* __restrict__ W_cat,
                                                float* __restrict__ bias) {
    const int blk = blockIdx.x;
    const int t   = threadIdx.x;
    if (blk < NBLK_A + NBLK_W) {
        const float* src0;
        unsigned short* dst;
        int row;
        if (blk < NBLK_A) {
            row = blk;
            dst = A_cat + (size_t)row * KTOT;
            int c8 = t << 3;
            src0 = (c8 < DH) ? (e_t + (size_t)row * DH + c8)
                             : (h_prev + (size_t)row * DH + (c8 - DH));
        } else {
            row = blk - NBLK_A;                 // n in [0,4096)
            int gate = (row >> 4) & 3;
            int h    = (row >> 6) * 16 + (row & 15);
            int srow = gate * DH + h;
            dst = W_cat + (size_t)row * KTOT;
            int c8 = t << 3;
            src0 = (c8 < DH) ? (W_x + (size_t)srow * DH + c8)
                             : (W_h + (size_t)srow * DH + (c8 - DH));
        }
        float4 f0 = ((const float4*)src0)[0];
        float4 f1 = ((const float4*)src0)[1];
        uint4 o;
        o.x = (unsigned)f2bf(f0.x) | ((unsigned)f2bf(f0.y) << 16);
        o.y = (unsigned)f2bf(f0.z) | ((unsigned)f2bf(f0.w) << 16);
        o.z = (unsigned)f2bf(f1.x) | ((unsigned)f2bf(f1.y) << 16);
        o.w = (unsigned)f2bf(f1.z) | ((unsigned)f2bf(f1.w) << 16);
        *(uint4*)(dst + t * 8) = o;
    } else {
        int gp = (blk - NBLK_A - NBLK_W) * 256 + t;   // n in [0,4096)
        int gate = (gp >> 4) & 3;
        int h    = (gp >> 6) * 16 + (gp & 15);
        int g    = gate * DH + h;
        bias[gp] = b_x[g] + b_h[g] + b_e[g];
    }
}

// ---------- 256x256 8-wave GEMM: A via LDS, B DIRECT from L2 ----------
//
// ROUND-6 RESTRUCTURE.  R2-R5 all landed at the serial sum of
// {LDS 256KB/tile, MFMA 2483 cyc/tile}: when all 8 waves burst ds_reads at
// a sync point, the shared per-CU LDS queue services them round-robin, so
// every wave's last read lands near the end of the burst -> no stagger,
// no read||MFMA overlap.  Fix = cut LDS traffic and kill the B-side burst:
//
//   * B (W_cat) is read DIRECTLY global->VGPR.  Per-XCD resident blocks
//     share n-col in {x, x+8} (grid x = n-col, dispatch round-robins x%8
//     across XCDs) -> W slice per XCD = 2MB < 4MB L2 -> L2-resident.
//     Fragment load is 16 rows x 64B contiguous = fully coalesced; no
//     swizzle needed.  Double-buffered one K-tile ahead on counted vmcnt.
//   * A stays LDS-staged (swizzled, GLL) -- A is streamed once, reused by
//     4 waves.  LDS/tile drops 256KB -> 160KB (reads 128K + GLL 32K).
//   * No B in LDS -> no mid-tile liveness hazard -> ONE barrier per tile.
//   * LDS total 64KB (A double-buffer only).
//
// Per-tile schedule (steady, MODE 2), per wave:
//   entry invariant: A(t) resident in As[t&1]; vmem outstanding = [b0(t) 4]
//   issue b1(t) x4                (vmem -> 8)
//   issue GLL A(t+1)->As_next x4  (vmem -> 12)
//   issue b0(t+1) x4              (vmem -> 16)
//   issue ds al0 x4, ah0 x4       (lgkm 8)
//   vmcnt(12)                     // b0(t) ready
//   lgkm(4)  -> C1: 16 MFMA (al0 x b0)
//   issue ds al1 x4 (reuse al regs; WAR safe: C1 already issued)
//   lgkm(4)  -> C2: 16 MFMA (ah0 x b0)
//   issue ds ah1 x4 (reuse ah regs)
//   vmcnt(8)                      // b1(t) ready
//   lgkm(4)  -> C3: 16 MFMA (al1 x b1)
//   lgkm(0)  -> C4: 16 MFMA (ah1 x b1)
//   vmcnt(4)                      // GLL A(t+1) landed; b0(t+1) in flight
//   s_barrier                     // all waves: A(t) reads retired, A(t+1) ready
// LIVENESS: GLL A(t+1)->As_next: As_next's last reads are tile t-1's C3/C4,
// lgkm-retired before t-1's end barrier -> safe.  al1/ah1 reg reuse: ds_read
// issues after the consuming MFMAs (in-order issue reads operands first).
// vmcnt never drains to 0 until the tail tile.

#define GLL(srcp, dstp) \
    __builtin_amdgcn_global_load_lds( \
        (const __attribute__((address_space(1))) void*)(srcp), \
        (__attribute__((address_space(3))) void*)(dstp), 16, 0, 0)

// one half-tile = 128 rows x 64 cols bf16 = 2 GLL/wave (8 waves x 64 lanes x 16B)
#define STAGE_HALF(g, buf, h, kt) do { \
    GLL((g) + ((size_t)((h) * 128)      * KTOT) + (size_t)(kt) * 64, (buf) + (((h) * 128)      + w8) * 128); \
    GLL((g) + ((size_t)((h) * 128 + 64) * KTOT) + (size_t)(kt) * 64, (buf) + (((h) * 128 + 64) + w8) * 128); \
} while (0)

#define SB() __builtin_amdgcn_sched_barrier(0)

#define WAIT_LGKM(n) do { SB(); asm volatile("s_waitcnt lgkmcnt(" #n ")" ::: "memory"); SB(); } while (0)
#define WAIT_VM(n)   do { SB(); asm volatile("s_waitcnt vmcnt(" #n ")"   ::: "memory"); SB(); } while (0)

template <int MODE>  // 2 = steady (issue b1, GLL A(t+1), b0(t+1); vmcnt 12/8/4; barrier)
                     // 0 = tile 31 (issue b1 only; vmcnt 4/0; no GLL, no barrier)
__device__ __forceinline__ void do_tile(
    int kt,
    unsigned char* As_cur, unsigned char* As_next,
    const unsigned short* __restrict__ gA, const unsigned short* __restrict__ gBrow,
    int w8, int rowA, int xg0, int xg1,
    bf16x8 (&b0)[4], bf16x8 (&b0n)[4],
    f32x4 (&acc)[8][4])
{
    bf16x8 al[4], ah[4], b1[4];

    // ---- issue b1(t): B frags kk=1 (4 x global_load_dwordx4) ----
#pragma unroll
    for (int ni = 0; ni < 4; ++ni)
        b1[ni] = *(const bf16x8*)(gBrow + (size_t)ni * (16 * KTOT) + (size_t)kt * 64 + 32);
    SB();
    // ---- issue GLL A(t+1) -> As_next ----
    if constexpr (MODE == 2) {
        STAGE_HALF(gA, As_next, 0, kt + 1);
        STAGE_HALF(gA, As_next, 1, kt + 1);
        SB();
        // ---- issue b0(t+1): B frags kk=0 of next tile ----
#pragma unroll
        for (int ni = 0; ni < 4; ++ni)
            b0n[ni] = *(const bf16x8*)(gBrow + (size_t)ni * (16 * KTOT) + (size_t)(kt + 1) * 64);
        SB();
    }

    // ---- issue A reads kk0: al0(4), ah0(4) ----
#pragma unroll
    for (int mi = 0; mi < 4; ++mi)
        al[mi] = *(const bf16x8*)(As_cur + rowA + mi * 2048 + xg0);
    SB();
#pragma unroll
    for (int mi = 0; mi < 4; ++mi)
        ah[mi] = *(const bf16x8*)(As_cur + rowA + (4 + mi) * 2048 + xg0);
    SB();

    // ---- C1: lo x kk0 (needs b0(t) + al0) ----
    if constexpr (MODE == 2) { WAIT_VM(12); } else { WAIT_VM(4); }
    WAIT_LGKM(4);
    __builtin_amdgcn_s_setprio(1);
#pragma unroll
    for (int mi = 0; mi < 4; ++mi)
#pragma unroll
        for (int ni = 0; ni < 4; ++ni)
            acc[mi][ni] = __builtin_amdgcn_mfma_f32_16x16x32_bf16(al[mi], b0[ni], acc[mi][ni], 0, 0, 0);
    __builtin_amdgcn_s_setprio(0);
    SB();

    // ---- issue A reads kk1 into al regs (WAR safe: C1 issued) ----
#pragma unroll
    for (int mi = 0; mi < 4; ++mi)
        al[mi] = *(const bf16x8*)(As_cur + rowA + mi * 2048 + xg1);
    SB();

    // ---- C2: hi x kk0 (needs ah0; al1 in flight) ----
    WAIT_LGKM(4);
    __builtin_amdgcn_s_setprio(1);
#pragma unroll
    for (int mi = 0; mi < 4; ++mi)
#pragma unroll
        for (int ni = 0; ni < 4; ++ni)
            acc[4 + mi][ni] = __builtin_amdgcn_mfma_f32_16x16x32_bf16(ah[mi], b0[ni], acc[4 + mi][ni], 0, 0, 0);
    __builtin_amdgcn_s_setprio(0);
    SB();

    // ---- issue A reads kk1-hi into ah regs ----
#pragma unroll
    for (int mi = 0; mi < 4; ++mi)
        ah[mi] = *(const bf16x8*)(As_cur + rowA + (4 + mi) * 2048 + xg1);
    SB();

    // ---- C3: lo x kk1 (needs b1(t) + al1) ----
    if constexpr (MODE == 2) { WAIT_VM(8); } else { WAIT_VM(0); }
    WAIT_LGKM(4);
    __builtin_amdgcn_s_setprio(1);
#pragma unroll
    for (int mi = 0; mi < 4; ++mi)
#pragma unroll
        for (int ni = 0; ni < 4; ++ni)
            acc[mi][ni] = __builtin_amdgcn_mfma_f32_16x16x32_bf16(al[mi], b1[ni], acc[mi][ni], 0, 0, 0);
    __builtin_amdgcn_s_setprio(0);
    SB();

    // ---- C4: hi x kk1 ----
    WAIT_LGKM(0);
    __builtin_amdgcn_s_setprio(1);
#pragma unroll
    for (int mi = 0; mi < 4; ++mi)
#pragma unroll
        for (int ni = 0; ni < 4; ++ni)
            acc[4 + mi][ni] = __builtin_amdgcn_mfma_f32_16x16x32_bf16(ah[mi], b1[ni], acc[4 + mi][ni], 0, 0, 0);
    __builtin_amdgcn_s_setprio(0);
    SB();

    // ---- tile end: A(t+1) landed (b0(t+1) stays in flight); sync waves ----
    if constexpr (MODE == 2) {
        WAIT_VM(4);
        __builtin_amdgcn_s_barrier();
        SB();
    }
}

__global__ __launch_bounds__(512, 2) void lstm_gemm(
    const unsigned short* __restrict__ A,
    const unsigned short* __restrict__ Wc,
    const float* __restrict__ bias,
    const float* __restrict__ c_prev,
    float* __restrict__ h_out,
    float* __restrict__ c_out)
{
    __shared__ __align__(16) unsigned char lds[65536];   // A double-buffer only

    const int tid = threadIdx.x;
    const int w   = tid >> 6;          // wave 0..7
    const int l   = tid & 63;          // lane
    const int wm  = w >> 2, wn = w & 3;
    const int m0  = blockIdx.y * 256;
    const int n0  = blockIdx.x * 256;
    const int w8  = w * 8;

    f32x4 acc[8][4];
#pragma unroll
    for (int i = 0; i < 8; ++i)
#pragma unroll
        for (int j = 0; j < 4; ++j) acc[i][j] = {0.f, 0.f, 0.f, 0.f};

    // A staging: wave w, lane l -> tile row = base + w*8 + (l>>3),
    // physical granule p = l&7, pre-swizzled source granule g = p ^ (row&7)
    const int srow = w8 + (l >> 3);
    const int scol = ((l & 7) ^ ((l >> 3) & 7)) * 8;   // element offset in 64-wide K-tile
    const unsigned short* gA = A + (size_t)(m0 + srow) * KTOT + scol;

    unsigned char* As0 = lds;
    unsigned char* As1 = lds + 32768;

    const int lane15 = l & 15;
    const int quad   = l >> 4;
    const int rowA = (wm * 128 + lane15) * 128;          // byte offset of A fragment row base
    const int xg0  = ((0 + quad) ^ (lane15 & 7)) * 16;   // kk=0 swizzled granule
    const int xg1  = ((4 + quad) ^ (lane15 & 7)) * 16;   // kk=1

    // B direct-load base: lane l covers row n0 + wn*64 + ni*16 + lane15,
    // elements kt*64 + kk*32 + quad*8 (16B, coalesced 64B per 16-row group)
    const unsigned short* gBrow = Wc + (size_t)(n0 + wn * 64 + lane15) * KTOT + quad * 8;

    bf16x8 b0A[4], b0B[4];

    // ---- prologue: GLL A(0) -> As0; issue b0(0) ----
    STAGE_HALF(gA, As0, 0, 0);
    STAGE_HALF(gA, As0, 1, 0);
    SB();
#pragma unroll
    for (int ni = 0; ni < 4; ++ni)
        b0A[ni] = *(const bf16x8*)(gBrow + (size_t)ni * (16 * KTOT));
    SB();
    asm volatile("s_waitcnt vmcnt(4)" ::: "memory");   // A(0) resident; b0(0) in flight
    SB();
    __builtin_amdgcn_s_barrier();
    SB();

#pragma unroll 1
    for (int kt2 = 0; kt2 < 15; ++kt2) {
        do_tile<2>(2 * kt2,     As0, As1, gA, gBrow, w8, rowA, xg0, xg1, b0A, b0B, acc);
        do_tile<2>(2 * kt2 + 1, As1, As0, gA, gBrow, w8, rowA, xg0, xg1, b0B, b0A, acc);
    }
    do_tile<2>(30, As0, As1, gA, gBrow, w8, rowA, xg0, xg1, b0A, b0B, acc);
    do_tile<0>(31, As1, As0, gA, gBrow, w8, rowA, xg0, xg1, b0B, b0A, acc);

    // ---------- fused LSTM epilogue (shuffle-free via gate-deinterleave) ----
    // C/D layout: col = lane&15 (n), row = quad*4 + reg (m).
    // N-packing puts gate = nj, h = ((n0+wn*64)>>6)*16 + lane15 for this wave:
    // acc[mi][0..3] are (zf,zi,zo,zc) of the SAME h, for 4 consecutive m rows.
    float biasv[4];
#pragma unroll
    for (int nj = 0; nj < 4; ++nj)
        biasv[nj] = bias[n0 + wn * 64 + nj * 16 + lane15];

    const int hcol = ((n0 + wn * 64) >> 6) * 16 + lane15;   // h index for this lane

#pragma unroll
    for (int mi = 0; mi < 8; ++mi) {
        const int mbase = m0 + wm * 128 + mi * 16 + quad * 4;
        f32x4 zf4 = acc[mi][0];
        f32x4 zi4 = acc[mi][1];
        f32x4 zo4 = acc[mi][2];
        f32x4 zc4 = acc[mi][3];
#pragma unroll
        for (int r = 0; r < 4; ++r) {
            float zf = zf4[r] + biasv[0];
            float zi = zi4[r] + biasv[1];
            float zo = zo4[r] + biasv[2];
            float zc = zc4[r] + biasv[3];

            float gf = fast_sigmoid(zf);
            float gi = fast_sigmoid(zi);
            float go = fast_sigmoid(zo);
            float mh = fast_tanh(zc);

            const size_t off = (size_t)(mbase + r) * DH + hcol;
            float cp = c_prev[off];
            float ct = gf * cp + gi * mh;
            float ht = go * fast_tanh(ct);
            h_out[off] = ht;
            c_out[off] = ct;
        }
    }
}

// ---------- launch ----------
extern "C" void kernel_launch(void* const* d_in, const int* in_sizes, int n_in,
                              void* d_out, int out_size, void* d_ws, size_t ws_size,
                              hipStream_t stream) {
    const float* e_t     = (const float*)d_in[0];
    const float* h_prev  = (const float*)d_in[1];
    const float* c_prev  = (const float*)d_in[2];
    const float* W_x     = (const float*)d_in[3];
    const float* b_x     = (const float*)d_in[4];
    const float* W_h     = (const float*)d_in[5];
    const float* b_h     = (const float*)d_in[6];
    const float* b_extra = (const float*)d_in[7];

    float* h_out = (float*)d_out;
    float* c_out = h_out + (size_t)B_ROWS * DH;

    // workspace layout: A_cat (32MB) | W_cat (16MB) | bias (16KB)
    unsigned short* A_cat = (unsigned short*)d_ws;
    unsigned short* W_cat = (unsigned short*)((char*)d_ws + (size_t)B_ROWS * KTOT * 2);
    float*          bias  = (float*)((char*)d_ws + (size_t)B_ROWS * KTOT * 2 + (size_t)NTOT * KTOT * 2);

    pack_all<<<NBLK_A + NBLK_W + NBLK_BIAS, 256, 0, stream>>>(
        e_t, h_prev, W_x, W_h, b_x, b_h, b_extra, A_cat, W_cat, bias);
    lstm_gemm<<<dim3(NTOT / 256, B_ROWS / 256), 512, 0, stream>>>(
        A_cat, W_cat, bias, c_prev, h_out, c_out);
}

// Round 7
// 298.570 us; speedup vs baseline: 1.2011x; 1.2011x over previous
//
#include <hip/hip_runtime.h>
#include <stdint.h>

// Problem constants (fixed by reference)
#define B_ROWS 8192
#define DH     1024      // D == H == 1024
#define KTOT   2048      // D + H (concatenated K)
#define NTOT   4096      // 4*H columns (gate-deinterleaved packing, see below)

typedef __attribute__((ext_vector_type(8))) __bf16 bf16x8;
typedef __attribute__((ext_vector_type(4))) float  f32x4;

// ---------- helpers ----------
__device__ __forceinline__ unsigned short f2bf(float f) {
    unsigned int u = __float_as_uint(f);
    u += 0x7FFFu + ((u >> 16) & 1u);   // round-to-nearest-even
    return (unsigned short)(u >> 16);
}

__device__ __forceinline__ float fast_sigmoid(float x) {
    return 1.0f / (1.0f + __expf(-x));
}
__device__ __forceinline__ float fast_tanh(float x) {
    float e = __expf(fminf(-2.0f * x, 80.0f));   // clamp avoids inf/inf
    return (1.0f - e) / (1.0f + e);
}

// ---------- single fused pack kernel (unchanged, verified) ----------
// N-space packing (gate-deinterleaved for the shuffle-free epilogue):
//   W_cat row n holds W row g = gate*DH + h with
//     gate = (n>>4) & 3,  h = (n>>6)*16 + (n&15)
//   bias[] packed identically.  The GEMM is invariant to this column perm.
#define NBLK_A (B_ROWS)            // one block packs one 2048-elem row
#define NBLK_W (NTOT)
#define NBLK_BIAS (NTOT / 256)

__global__ __launch_bounds__(256) void pack_all(const float* __restrict__ e_t,
                                                const float* __restrict__ h_prev,
                                                const float* __restrict__ W_x,
                                                const float* __restrict__ W_h,
                                                const float* __restrict__ b_x,
                                                const float* __restrict__ b_h,
                                                const float* __restrict__ b_e,
                                                unsigned short* __restrict__ A_cat,
                                                unsigned short* __restrict__ W_cat,
                                                float* __restrict__ bias) {
    const int blk = blockIdx.x;
    const int t   = threadIdx.x;
    if (blk < NBLK_A + NBLK_W) {
        const float* src0;
        unsigned short* dst;
        int row;
        if (blk < NBLK_A) {
            row = blk;
            dst = A_cat + (size_t)row * KTOT;
            int c8 = t << 3;
            src0 = (c8 < DH) ? (e_t + (size_t)row * DH + c8)
                             : (h_prev + (size_t)row * DH + (c8 - DH));
        } else {
            row = blk - NBLK_A;                 // n in [0,4096)
            int gate = (row >> 4) & 3;
            int h    = (row >> 6) * 16 + (row & 15);
            int srow = gate * DH + h;
            dst = W_cat + (size_t)row * KTOT;
            int c8 = t << 3;
            src0 = (c8 < DH) ? (W_x + (size_t)srow * DH + c8)
                             : (W_h + (size_t)srow * DH + (c8 - DH));
        }
        float4 f0 = ((const float4*)src0)[0];
        float4 f1 = ((const float4*)src0)[1];
        uint4 o;
        o.x = (unsigned)f2bf(f0.x) | ((unsigned)f2bf(f0.y) << 16);
        o.y = (unsigned)f2bf(f0.z) | ((unsigned)f2bf(f0.w) << 16);
        o.z = (unsigned)f2bf(f1.x) | ((unsigned)f2bf(f1.y) << 16);
        o.w = (unsigned)f2bf(f1.z) | ((unsigned)f2bf(f1.w) << 16);
        *(uint4*)(dst + t * 8) = o;
    } else {
        int gp = (blk - NBLK_A - NBLK_W) * 256 + t;   // n in [0,4096)
        int gate = (gp >> 4) & 3;
        int h    = (gp >> 6) * 16 + (gp & 15);
        int g    = gate * DH + h;
        bias[gp] = b_x[g] + b_h[g] + b_e[g];
    }
}

// ---------- 256x256 8-wave GEMM: 4 phases/tile, reads ONE PHASE AHEAD -------
//
// BM=BN=256, BK=64, 8 waves (2M x 4N), LDS 128 KiB (2-parity A/B buffers).
// XOR granule swizzle (verified): logical 16B-granule g of row r stored at
// physical p = g ^ (r&7); applied on the global SOURCE address; fragment
// reads use p = (kk*4+quad) ^ (lane15&7).
//
// ROUND-7: the missing m218 cell = {many phases} x {reads issued one phase
// ahead} x {counted lgkm}.  A wave OCCUPIES the matrix pipe during its MFMA
// cluster (~19.4 cyc/MFMA issue); overlap happens only if the lgkm wait at
// the top of a phase covers reads issued in the PREVIOUS phase (serviced
// under that phase's MFMA).  R4 waited on same-phase reads (exposed); R5
// burst all reads at once (first wait uncovered).  Here every phase issues
// the NEXT phase's operands, then waits (counted) for operands issued one
// phase ago.
//
// Per-tile ledger (steady; per-wave ds queue, in-order retire):
//   enter P1: outstanding ds = [b0(t) 4, al0(t) 4]   (issued P4(t-1))
//   P1: issue ah0(t)4      ; GLL B(t+1)h1, A(t+1)h0 ; bar; lgkm(4) ; C1 lo.kk0 ; bar
//   P2: issue al1(t)4,b1(t)4; GLL A(t+1)h1          ; bar; lgkm(8) ; C2 hi.kk0 ; bar
//   P3: issue ah1(t)4      ;                          bar; vmcnt(0); lgkm(4) ; C3 lo.kk1 ; bar
//   P4: issue b0(t+1)4,al0(t+1)4 (from NEXT parity) ; GLL B(t+2)h0 ; bar; lgkm(8) ; C4 hi.kk1 ; bar
// Frag regs al/ah/b0/b1 are WAR-reused: the overwriting ds_read issues
// AFTER the consuming MFMA in program order.
// Staging liveness: A(t+1)->nxtA at P1/P2 (nxtA free since P4(t-1) endbar);
// B(t+1)h1->nxtB at P1 (nxtB free since P3(t-1) endbar; h0 staged P4(t-1));
// B(t+2)h0->curB at P4 (curB free after P3(t) endbar: b1(t) retired at P3).
// vmcnt(0) at P3 drains GLLs whose newest is one full phase old (~200cy
// residual) and guarantees A(t+1),B(t+1) resident before P4's read-ahead.
// GLL carry across tiles: exactly [B(t+1)h0 2] enters each tile.

#define GLL(srcp, dstp) \
    __builtin_amdgcn_global_load_lds( \
        (const __attribute__((address_space(1))) void*)(srcp), \
        (__attribute__((address_space(3))) void*)(dstp), 16, 0, 0)

// one half-tile = 128 rows x 64 cols bf16 = 2 GLL/wave (8 waves x 64 lanes x 16B)
#define STAGE_HALF(g, buf, h, kt) do { \
    GLL((g) + ((size_t)((h) * 128)      * KTOT) + (size_t)(kt) * 64, (buf) + (((h) * 128)      + w8) * 128); \
    GLL((g) + ((size_t)((h) * 128 + 64) * KTOT) + (size_t)(kt) * 64, (buf) + (((h) * 128 + 64) + w8) * 128); \
} while (0)

#define SB() __builtin_amdgcn_sched_barrier(0)

#define WAIT_LGKM(n) do { SB(); asm volatile("s_waitcnt lgkmcnt(" #n ")" ::: "memory"); SB(); } while (0)
#define WAIT_VM(n)   do { SB(); asm volatile("s_waitcnt vmcnt(" #n ")"   ::: "memory"); SB(); } while (0)

#define MFMA_CL(ACC_OFF, AREG, BREG) do { \
    __builtin_amdgcn_s_setprio(1); \
    _Pragma("unroll") \
    for (int mi = 0; mi < 4; ++mi) \
        _Pragma("unroll") \
        for (int ni = 0; ni < 4; ++ni) \
            acc[(ACC_OFF) + mi][ni] = __builtin_amdgcn_mfma_f32_16x16x32_bf16((AREG)[mi], (BREG)[ni], acc[(ACC_OFF) + mi][ni], 0, 0, 0); \
    __builtin_amdgcn_s_setprio(0); \
    SB(); \
} while (0)

template <int MODE>  // 2 = steady, 1 = tile 30 (skip P4 GLL), 0 = tile 31 (last)
__device__ __forceinline__ void do_tile(
    int kt,
    unsigned char* As_cur, unsigned char* As_nxt,
    unsigned char* Bs_cur, unsigned char* Bs_nxt,
    const unsigned short* __restrict__ gA, const unsigned short* __restrict__ gB,
    int w8, int rowA, int rowB, int xg0, int xg1,
    bf16x8 (&al)[4], bf16x8 (&ah)[4], bf16x8 (&b0)[4], bf16x8 (&b1)[4],
    f32x4 (&acc)[8][4])
{
    // ================ P1: consume {al0,b0}; issue ah0; stage Bh1/Ah0(t+1) ===
#pragma unroll
    for (int mi = 0; mi < 4; ++mi)
        ah[mi] = *(const bf16x8*)(As_cur + rowA + (4 + mi) * 2048 + xg0);
    SB();
    if constexpr (MODE >= 1) {
        STAGE_HALF(gB, Bs_nxt, 1, kt + 1);
        STAGE_HALF(gA, As_nxt, 0, kt + 1);
        SB();
    }
    __builtin_amdgcn_s_barrier();
    WAIT_LGKM(4);                       // retires b0(t), al0(t)
    MFMA_CL(0, al, b0);                 // C1: lo x kk0
    __builtin_amdgcn_s_barrier();
    SB();

    // ================ P2: consume {ah0,b0}; issue al1,b1; stage Ah1(t+1) ====
#pragma unroll
    for (int mi = 0; mi < 4; ++mi)
        al[mi] = *(const bf16x8*)(As_cur + rowA + mi * 2048 + xg1);       // al1
    SB();
#pragma unroll
    for (int ni = 0; ni < 4; ++ni)
        b1[ni] = *(const bf16x8*)(Bs_cur + rowB + ni * 2048 + xg1);
    SB();
    if constexpr (MODE >= 1) {
        STAGE_HALF(gA, As_nxt, 1, kt + 1);
        SB();
    }
    __builtin_amdgcn_s_barrier();
    WAIT_LGKM(8);                       // retires ah0(t)
    MFMA_CL(4, ah, b0);                 // C2: hi x kk0
    __builtin_amdgcn_s_barrier();
    SB();

    // ================ P3: consume {al1,b1}; issue ah1; vmcnt gate ===========
#pragma unroll
    for (int mi = 0; mi < 4; ++mi)
        ah[mi] = *(const bf16x8*)(As_cur + rowA + (4 + mi) * 2048 + xg1);  // ah1
    SB();
    __builtin_amdgcn_s_barrier();
    WAIT_VM(0);                         // A(t+1), B(t+1) staging landed
    WAIT_LGKM(4);                       // retires al1(t), b1(t)
    MFMA_CL(0, al, b1);                 // C3: lo x kk1
    __builtin_amdgcn_s_barrier();       // frees curB for B(t+2) staging
    SB();

    // ================ P4: consume {ah1,b1}; read-ahead t+1; stage Bh0(t+2) ==
    if constexpr (MODE >= 1) {
#pragma unroll
        for (int ni = 0; ni < 4; ++ni)
            b0[ni] = *(const bf16x8*)(Bs_nxt + rowB + ni * 2048 + xg0);    // b0(t+1)
        SB();
#pragma unroll
        for (int mi = 0; mi < 4; ++mi)
            al[mi] = *(const bf16x8*)(As_nxt + rowA + mi * 2048 + xg0);    // al0(t+1)
        SB();
    }
    if constexpr (MODE == 2) {
        STAGE_HALF(gB, Bs_cur, 0, kt + 2);
        SB();
    }
    __builtin_amdgcn_s_barrier();
    if constexpr (MODE >= 1) {
        WAIT_LGKM(8);                   // retires ah1(t); leaves b0/al0(t+1)
    } else {
        WAIT_LGKM(0);                   // last tile: retire ah1
    }
    MFMA_CL(4, ah, b1);                 // C4: hi x kk1
    if constexpr (MODE >= 1) {
        __builtin_amdgcn_s_barrier();   // frees curA for A(t+2) staging
        SB();
    }
}

__global__ __launch_bounds__(512, 2) void lstm_gemm(
    const unsigned short* __restrict__ A,
    const unsigned short* __restrict__ Wc,
    const float* __restrict__ bias,
    const float* __restrict__ c_prev,
    float* __restrict__ h_out,
    float* __restrict__ c_out)
{
    __shared__ __align__(16) unsigned char lds[131072];

    const int tid = threadIdx.x;
    const int w   = tid >> 6;          // wave 0..7
    const int l   = tid & 63;          // lane
    const int wm  = w >> 2, wn = w & 3;
    const int m0  = blockIdx.y * 256;
    const int n0  = blockIdx.x * 256;
    const int w8  = w * 8;

    f32x4 acc[8][4];
#pragma unroll
    for (int i = 0; i < 8; ++i)
#pragma unroll
        for (int j = 0; j < 4; ++j) acc[i][j] = {0.f, 0.f, 0.f, 0.f};

    // A/B staging: wave w, lane l -> tile row = base + w*8 + (l>>3),
    // physical granule p = l&7, pre-swizzled source granule g = p ^ (row&7)
    const int srow = w8 + (l >> 3);
    const int scol = ((l & 7) ^ ((l >> 3) & 7)) * 8;   // element offset in 64-wide K-tile
    const unsigned short* gA = A  + (size_t)(m0 + srow) * KTOT + scol;
    const unsigned short* gB = Wc + (size_t)(n0 + srow) * KTOT + scol;

    unsigned char* As0 = lds;
    unsigned char* As1 = lds + 32768;
    unsigned char* Bs0 = lds + 65536;
    unsigned char* Bs1 = lds + 98304;

    const int lane15 = l & 15;
    const int quad   = l >> 4;
    const int rowA = (wm * 128 + lane15) * 128;          // byte offset of A fragment row base
    const int rowB = (wn * 64  + lane15) * 128;
    const int xg0  = ((0 + quad) ^ (lane15 & 7)) * 16;   // kk=0 swizzled granule
    const int xg1  = ((4 + quad) ^ (lane15 & 7)) * 16;   // kk=1

    bf16x8 al[4], ah[4], b0[4], b1[4];

    // ---- prologue: A(0), B(0), B(1)h0 staged; [b0(0), al0(0)] issued ----
    STAGE_HALF(gA, As0, 0, 0);
    STAGE_HALF(gA, As0, 1, 0);
    STAGE_HALF(gB, Bs0, 0, 0);
    STAGE_HALF(gB, Bs0, 1, 0);
    STAGE_HALF(gB, Bs1, 0, 1);
    SB();
    asm volatile("s_waitcnt vmcnt(2)" ::: "memory");   // A(0),B(0) landed; B(1)h0 in flight
    SB();
    __builtin_amdgcn_s_barrier();
    SB();
#pragma unroll
    for (int ni = 0; ni < 4; ++ni)
        b0[ni] = *(const bf16x8*)(Bs0 + rowB + ni * 2048 + xg0);
#pragma unroll
    for (int mi = 0; mi < 4; ++mi)
        al[mi] = *(const bf16x8*)(As0 + rowA + mi * 2048 + xg0);
    SB();

#pragma unroll 1
    for (int kt2 = 0; kt2 < 15; ++kt2) {
        do_tile<2>(2 * kt2,     As0, As1, Bs0, Bs1, gA, gB, w8, rowA, rowB, xg0, xg1, al, ah, b0, b1, acc);
        do_tile<2>(2 * kt2 + 1, As1, As0, Bs1, Bs0, gA, gB, w8, rowA, rowB, xg0, xg1, al, ah, b0, b1, acc);
    }
    do_tile<1>(30, As0, As1, Bs0, Bs1, gA, gB, w8, rowA, rowB, xg0, xg1, al, ah, b0, b1, acc);
    do_tile<0>(31, As1, As0, Bs1, Bs0, gA, gB, w8, rowA, rowB, xg0, xg1, al, ah, b0, b1, acc);

    // ---------- fused LSTM epilogue (shuffle-free via gate-deinterleave) ----
    // C/D layout: col = lane&15 (n), row = quad*4 + reg (m).
    // N-packing puts gate = nj, h = ((n0+wn*64)>>6)*16 + lane15 for this wave:
    // acc[mi][0..3] are (zf,zi,zo,zc) of the SAME h, for 4 consecutive m rows.
    float biasv[4];
#pragma unroll
    for (int nj = 0; nj < 4; ++nj)
        biasv[nj] = bias[n0 + wn * 64 + nj * 16 + lane15];

    const int hcol = ((n0 + wn * 64) >> 6) * 16 + lane15;   // h index for this lane

#pragma unroll
    for (int mi = 0; mi < 8; ++mi) {
        const int mbase = m0 + wm * 128 + mi * 16 + quad * 4;
        f32x4 zf4 = acc[mi][0];
        f32x4 zi4 = acc[mi][1];
        f32x4 zo4 = acc[mi][2];
        f32x4 zc4 = acc[mi][3];
#pragma unroll
        for (int r = 0; r < 4; ++r) {
            float zf = zf4[r] + biasv[0];
            float zi = zi4[r] + biasv[1];
            float zo = zo4[r] + biasv[2];
            float zc = zc4[r] + biasv[3];

            float gf = fast_sigmoid(zf);
            float gi = fast_sigmoid(zi);
            float go = fast_sigmoid(zo);
            float mh = fast_tanh(zc);

            const size_t off = (size_t)(mbase + r) * DH + hcol;
            float cp = c_prev[off];
            float ct = gf * cp + gi * mh;
            float ht = go * fast_tanh(ct);
            h_out[off] = ht;
            c_out[off] = ct;
        }
    }
}

// ---------- launch ----------
extern "C" void kernel_launch(void* const* d_in, const int* in_sizes, int n_in,
                              void* d_out, int out_size, void* d_ws, size_t ws_size,
                              hipStream_t stream) {
    const float* e_t     = (const float*)d_in[0];
    const float* h_prev  = (const float*)d_in[1];
    const float* c_prev  = (const float*)d_in[2];
    const float* W_x     = (const float*)d_in[3];
    const float* b_x     = (const float*)d_in[4];
    const float* W_h     = (const float*)d_in[5];
    const float* b_h     = (const float*)d_in[6];
    const float* b_extra = (const float*)d_in[7];

    float* h_out = (float*)d_out;
    float* c_out = h_out + (size_t)B_ROWS * DH;

    // workspace layout: A_cat (32MB) | W_cat (16MB) | bias (16KB)
    unsigned short* A_cat = (unsigned short*)d_ws;
    unsigned short* W_cat = (unsigned short*)((char*)d_ws + (size_t)B_ROWS * KTOT * 2);
    float*          bias  = (float*)((char*)d_ws + (size_t)B_ROWS * KTOT * 2 + (size_t)NTOT * KTOT * 2);

    pack_all<<<NBLK_A + NBLK_W + NBLK_BIAS, 256, 0, stream>>>(
        e_t, h_prev, W_x, W_h, b_x, b_h, b_extra, A_cat, W_cat, bias);
    lstm_gemm<<<dim3(NTOT / 256, B_ROWS / 256), 512, 0, stream>>>(
        A_cat, W_cat, bias, c_prev, h_out, c_out);
}